// Round 6
// baseline (362.937 us; speedup 1.0000x reference)
//
#include <hip/hip_runtime.h>
#include <math.h>

#define N_NODES 100000
#define N_EDGES 800000
#define NEG_SLOPE 0.2f

typedef __attribute__((ext_vector_type(8))) short short8;
typedef __attribute__((ext_vector_type(4))) float floatx4;

__device__ __forceinline__ float lrelu(float x) { return x > 0.f ? x : NEG_SLOPE * x; }

__device__ __forceinline__ unsigned bf16_rne(float f) {
    unsigned u = __float_as_uint(f);
    return (u + 0x7fffu + ((u >> 16) & 1u)) >> 16;
}
__device__ __forceinline__ unsigned bfpack(float lo, float hi) {
    return bf16_rne(lo) | (bf16_rne(hi) << 16);
}
__device__ __forceinline__ float bflo(unsigned p) { return __uint_as_float(p << 16); }
__device__ __forceinline__ float bfhi(unsigned p) { return __uint_as_float(p & 0xffff0000u); }

#define ACC8(P, W)                                                   \
    acc[0] = fmaf(bflo((P).x), (W), acc[0]);                         \
    acc[1] = fmaf(bfhi((P).x), (W), acc[1]);                         \
    acc[2] = fmaf(bflo((P).y), (W), acc[2]);                         \
    acc[3] = fmaf(bfhi((P).y), (W), acc[3]);                         \
    acc[4] = fmaf(bflo((P).z), (W), acc[4]);                         \
    acc[5] = fmaf(bfhi((P).z), (W), acc[5]);                         \
    acc[6] = fmaf(bflo((P).w), (W), acc[6]);                         \
    acc[7] = fmaf(bfhi((P).w), (W), acc[7]);

// ---------------- hist (blocks 0..3124) + W-prep (blocks 3125..3252) ----------------
__global__ __launch_bounds__(256) void k_hist_wprep(const int* __restrict__ dst,
                                                    int* __restrict__ deg,
                                                    const float* __restrict__ W1,
                                                    const float* __restrict__ W2,
                                                    unsigned short* __restrict__ wt1,
                                                    unsigned short* __restrict__ wt2) {
    int b = blockIdx.x;
    if (b < 3125) {
        int e = b * 256 + threadIdx.x;
        if (e < N_EDGES) atomicAdd(&deg[dst[e]], 1);
    } else {
        int tid = (b - 3125) * 256 + threadIdx.x;   // 0..32767
        const float* W = (tid < 16384) ? W1 : W2;
        unsigned short* wt = (tid < 16384) ? wt1 : wt2;
        int t = tid & 16383;
        int n = t >> 7, k = t & 127;
        wt[t] = (unsigned short)bf16_rne(W[k * 128 + n]);
    }
}

// ---------------- single-dispatch exclusive scan over deg (98 blocks, spin-sync) ----------------
// 98 blocks co-resident (<< 256 CUs). bsums published + read via device-scope atomics.
__global__ __launch_bounds__(256) void k_scan(const int* __restrict__ deg,
                                              int* __restrict__ rs,
                                              int* __restrict__ cursor,
                                              int* __restrict__ bsums,
                                              int* __restrict__ done) {
    __shared__ int sd[256];
    int tid = threadIdx.x, b = blockIdx.x;
    int base = b * 1024 + tid * 4;
    int v0 = (base + 0 < N_NODES) ? deg[base + 0] : 0;
    int v1 = (base + 1 < N_NODES) ? deg[base + 1] : 0;
    int v2 = (base + 2 < N_NODES) ? deg[base + 2] : 0;
    int v3 = (base + 3 < N_NODES) ? deg[base + 3] : 0;
    int t = v0 + v1 + v2 + v3;
    sd[tid] = t;
    __syncthreads();
    int incl = t;
    for (int off = 1; off < 256; off <<= 1) {
        int x = (tid >= off) ? sd[tid - off] : 0;
        __syncthreads();
        incl += x;
        sd[tid] = incl;
        __syncthreads();
    }
    int excl = incl - t;

    // publish block total, then spin for all 98
    if (tid == 255) {
        atomicExch(&bsums[b], incl);
        __threadfence();
        atomicAdd(done, 1);
    }
    if (tid == 0) {
        while (atomicAdd(done, 0) < 98) { }
    }
    __syncthreads();

    // block offset = sum of bsums[0..b-1]
    int bv = (tid < b) ? atomicAdd(&bsums[tid], 0) : 0;
    __syncthreads();            // sd reuse
    sd[tid] = bv;
    __syncthreads();
    for (int off = 128; off > 0; off >>= 1) {
        if (tid < off) sd[tid] += sd[tid + off];
        __syncthreads();
    }
    int boff = sd[0];

    int p0 = excl + boff;
    if (base + 0 < N_NODES) { rs[base + 0] = p0; cursor[base + 0] = p0; }
    if (base + 1 < N_NODES) { rs[base + 1] = p0 + v0; cursor[base + 1] = p0 + v0; }
    if (base + 2 < N_NODES) { rs[base + 2] = p0 + v0 + v1; cursor[base + 2] = p0 + v0 + v1; }
    if (base + 3 < N_NODES) { rs[base + 3] = p0 + v0 + v1 + v2; cursor[base + 3] = p0 + v0 + v1 + v2; }
    if (b == 0 && tid == 0) rs[N_NODES] = N_EDGES;   // sentinel
}

__global__ void k_scatter(const int* __restrict__ src, const int* __restrict__ dst,
                          int* __restrict__ cursor, int* __restrict__ csr_src) {
    int e = blockIdx.x * blockDim.x + threadIdx.x;
    if (e < N_EDGES) {
        int d = dst[e];
        int p = atomicAdd(&cursor[d], 1);
        csr_src[p] = src[e];
    }
}

// ---------------- MFMA GEMM: h = X @ W (bf16 in, fp32 acc) + el/er epilogue ----------------
__global__ __launch_bounds__(256) void k_gemm(const void* __restrict__ Xv,
                                              const unsigned short* __restrict__ wt,
                                              const float* __restrict__ al,
                                              const float* __restrict__ ar,
                                              unsigned* __restrict__ Hb,
                                              float* __restrict__ EL,
                                              float* __restrict__ ER,
                                              int src_bf16) {
    __shared__ unsigned short wsh[128 * 128];   // 32 KB, swizzled [n][k] bf16
    int tid = threadIdx.x;
    int w = tid >> 6, lane = tid & 63;
    int q = lane >> 4, nl = lane & 15;
    int base = blockIdx.x * 128;

    const uint4* wt4 = (const uint4*)wt;
    #pragma unroll
    for (int i = 0; i < 8; i++) {
        int idx = tid + i * 256;                // 0..2047 chunks of 8 shorts
        int rn = idx >> 4, c8 = idx & 15;
        int kc = c8 >> 2, qq = c8 & 3;
        int slot = rn * 128 + ((kc ^ ((rn >> 2) & 3)) * 4 + (qq ^ (rn & 3))) * 8;
        *(uint4*)&wsh[slot] = wt4[idx];
    }

    short8 afr[2][4];
    int row0 = base + w * 32 + nl;
    if (!src_bf16) {
        const float4* X4 = (const float4*)Xv;
        #pragma unroll
        for (int rt = 0; rt < 2; rt++) {
            int rr = row0 + rt * 16; if (rr > N_NODES - 1) rr = N_NODES - 1;
            const float4* px = X4 + (size_t)rr * 32 + q * 2;
            #pragma unroll
            for (int kc = 0; kc < 4; kc++) {
                float4 u = px[kc * 8], v = px[kc * 8 + 1];
                short8 f;
                f[0] = (short)bf16_rne(u.x); f[1] = (short)bf16_rne(u.y);
                f[2] = (short)bf16_rne(u.z); f[3] = (short)bf16_rne(u.w);
                f[4] = (short)bf16_rne(v.x); f[5] = (short)bf16_rne(v.y);
                f[6] = (short)bf16_rne(v.z); f[7] = (short)bf16_rne(v.w);
                afr[rt][kc] = f;
            }
        }
    } else {
        const unsigned short* Xb = (const unsigned short*)Xv;
        #pragma unroll
        for (int rt = 0; rt < 2; rt++) {
            int rr = row0 + rt * 16; if (rr > N_NODES - 1) rr = N_NODES - 1;
            #pragma unroll
            for (int kc = 0; kc < 4; kc++)
                afr[rt][kc] = *(const short8*)(Xb + (size_t)rr * 128 + kc * 32 + q * 8);
        }
    }

    floatx4 acc[2][8];
    #pragma unroll
    for (int rt = 0; rt < 2; rt++)
        #pragma unroll
        for (int ct = 0; ct < 8; ct++)
            acc[rt][ct] = (floatx4){0.f, 0.f, 0.f, 0.f};

    __syncthreads();

    int sw_hi = (nl >> 2) & 3, sw_lo = nl & 3;
    #pragma unroll
    for (int ct = 0; ct < 8; ct++) {
        int rbase = (ct * 16 + nl) * 128;
        #pragma unroll
        for (int kc = 0; kc < 4; kc++) {
            short8 b = *(const short8*)&wsh[rbase + ((kc ^ sw_hi) * 4 + (q ^ sw_lo)) * 8];
            acc[0][ct] = __builtin_amdgcn_mfma_f32_16x16x32_bf16(afr[0][kc], b, acc[0][ct], 0, 0, 0);
            acc[1][ct] = __builtin_amdgcn_mfma_f32_16x16x32_bf16(afr[1][kc], b, acc[1][ct], 0, 0, 0);
        }
    }

    float all_[4], alh_[4], arl_[4], arh_[4];
    #pragma unroll
    for (int h = 0; h < 4; h++) {
        all_[h] = al[h * 32 + nl]; alh_[h] = al[h * 32 + 16 + nl];
        arl_[h] = ar[h * 32 + nl]; arh_[h] = ar[h * 32 + 16 + nl];
    }
    #pragma unroll
    for (int rt = 0; rt < 2; rt++) {
        #pragma unroll
        for (int r = 0; r < 4; r++) {
            int row = base + w * 32 + rt * 16 + q * 4 + r;
            bool valid = row < N_NODES;
            unsigned* hrow = Hb + (size_t)row * 64;
            #pragma unroll
            for (int ct = 0; ct < 8; ct++) {
                float vlo = acc[rt][ct][r];
                float vhi = __shfl_down(vlo, 1);
                if (valid && !(nl & 1)) hrow[ct * 8 + (nl >> 1)] = bfpack(vlo, vhi);
            }
            #pragma unroll
            for (int h = 0; h < 4; h++) {
                float pel = acc[rt][2 * h][r] * all_[h] + acc[rt][2 * h + 1][r] * alh_[h];
                float per = acc[rt][2 * h][r] * arl_[h] + acc[rt][2 * h + 1][r] * arh_[h];
                #pragma unroll
                for (int o = 1; o < 16; o <<= 1) {
                    pel += __shfl_xor(pel, o);
                    per += __shfl_xor(per, o);
                }
                if (valid && nl == 0) { EL[row * 4 + h] = pel; ER[row * 4 + h] = per; }
            }
        }
    }
}

// ---------------- gather v4: fused softmax+aggregate, cross-node pipelined ----------------
// One wave = 4 nodes. 16 lanes/edge (uint4 = full 256B H row), 4 groups x 2 = 8 edges per
// batch. While node nn is consumed, node nn+1's csr loads are in flight; node nn+1's H/EL
// loads are issued BEFORE node nn's merge+store, overlapping the random-gather latency.
__global__ __launch_bounds__(256) void k_gather(const int* __restrict__ rs,
                                                const int* __restrict__ csr,
                                                const float* __restrict__ EL,
                                                const float* __restrict__ ER,
                                                const unsigned* __restrict__ Hb,
                                                const float* __restrict__ bias,
                                                void* __restrict__ out,
                                                int final_layer) {
    int wid = (blockIdx.x * blockDim.x + threadIdx.x) >> 6;
    int lane = threadIdx.x & 63;
    int g = lane >> 4, l16 = lane & 15;
    int h = l16 >> 2;
    int n0 = wid * 4;
    if (n0 >= N_NODES) return;
    int nlast = min(4, N_NODES - n0);

    float bv[8];
    #pragma unroll
    for (int c = 0; c < 8; c++) bv[c] = bias[l16 * 8 + c];

    int sE[5];
    #pragma unroll
    for (int i = 0; i < 5; i++) sE[i] = rs[min(n0 + i, N_NODES)];
    float erh[4];
    #pragma unroll
    for (int i = 0; i < 4; i++) erh[i] = (n0 + i < N_NODES) ? ER[(n0 + i) * 4 + h] : 0.f;

    const uint4 zero4 = make_uint4(0, 0, 0, 0);

    // prime node 0
    int cs0 = 0, cs1 = 0; bool cv0, cv1;
    {
        int s = sE[0], e = sE[1];
        cv0 = (s + g) < e; cv1 = (s + 4 + g) < e;
        if (cv0) cs0 = csr[s + g];
        if (cv1) cs1 = csr[s + 4 + g];
    }
    uint4 cp0 = zero4, cp1 = zero4;
    float cel0 = 0.f, cel1 = 0.f;
    if (cv0) { cp0 = *(const uint4*)(Hb + (size_t)cs0 * 64 + l16 * 4); cel0 = EL[cs0 * 4 + h]; }
    if (cv1) { cp1 = *(const uint4*)(Hb + (size_t)cs1 * 64 + l16 * 4); cel1 = EL[cs1 * 4 + h]; }

    for (int nn = 0; nn < nlast; nn++) {
        int s = sE[nn], e = sE[nn + 1];

        // issue next node's index loads (stay in flight through this node's FMAs)
        int ns0 = 0, ns1 = 0; bool nv0 = false, nv1 = false;
        if (nn + 1 < nlast) {
            int s2 = sE[nn + 1], e2 = sE[nn + 2];
            nv0 = (s2 + g) < e2; nv1 = (s2 + 4 + g) < e2;
            if (nv0) ns0 = csr[s2 + g];
            if (nv1) ns1 = csr[s2 + 4 + g];
        }

        float acc[8] = {0.f, 0.f, 0.f, 0.f, 0.f, 0.f, 0.f, 0.f};
        float w0 = cv0 ? __expf(lrelu(cel0 + erh[nn])) : 0.f;
        float w1 = cv1 ? __expf(lrelu(cel1 + erh[nn])) : 0.f;
        float sa = w0 + w1;
        ACC8(cp0, w0);
        ACC8(cp1, w1);

        // remainder edges (deg > 8), unpipelined
        for (int j = s + 8; j < e; j += 8) {
            int j0 = j + g, j1 = j + 4 + g;
            bool b0 = j0 < e, b1 = j1 < e;
            int t0 = 0, t1 = 0;
            if (b0) t0 = csr[j0];
            if (b1) t1 = csr[j1];
            uint4 p0 = zero4, p1 = zero4;
            float e0 = 0.f, e1 = 0.f;
            if (b0) { p0 = *(const uint4*)(Hb + (size_t)t0 * 64 + l16 * 4); e0 = EL[t0 * 4 + h]; }
            if (b1) { p1 = *(const uint4*)(Hb + (size_t)t1 * 64 + l16 * 4); e1 = EL[t1 * 4 + h]; }
            float x0 = b0 ? __expf(lrelu(e0 + erh[nn])) : 0.f;
            float x1 = b1 ? __expf(lrelu(e1 + erh[nn])) : 0.f;
            sa += x0 + x1;
            ACC8(p0, x0);
            ACC8(p1, x1);
        }

        // prefetch next node's H/EL before this node's merge+store
        if (nn + 1 < nlast) {
            cp0 = zero4; cp1 = zero4; cel0 = 0.f; cel1 = 0.f;
            if (nv0) { cp0 = *(const uint4*)(Hb + (size_t)ns0 * 64 + l16 * 4); cel0 = EL[ns0 * 4 + h]; }
            if (nv1) { cp1 = *(const uint4*)(Hb + (size_t)ns1 * 64 + l16 * 4); cel1 = EL[ns1 * 4 + h]; }
            cv0 = nv0; cv1 = nv1;
        }

        // merge the 4 edge-groups
        #pragma unroll
        for (int c = 0; c < 8; c++) {
            acc[c] += __shfl_xor(acc[c], 16);
            acc[c] += __shfl_xor(acc[c], 32);
        }
        sa += __shfl_xor(sa, 16);
        sa += __shfl_xor(sa, 32);
        float inv = (e > s) ? 1.f / sa : 0.f;

        int n = n0 + nn;
        float r[8];
        #pragma unroll
        for (int c = 0; c < 8; c++) r[c] = acc[c] * inv + bv[c];

        if (!final_layer) {
            if (g == 0) {
                uint4 pk;
                pk.x = bfpack(fmaxf(r[0], 0.f), fmaxf(r[1], 0.f));
                pk.y = bfpack(fmaxf(r[2], 0.f), fmaxf(r[3], 0.f));
                pk.z = bfpack(fmaxf(r[4], 0.f), fmaxf(r[5], 0.f));
                pk.w = bfpack(fmaxf(r[6], 0.f), fmaxf(r[7], 0.f));
                *(uint4*)((unsigned*)out + (size_t)n * 64 + l16 * 4) = pk;
            }
        } else {
            // mean over heads: lanes l16, l16^4, l16^8 hold the 4 heads
            #pragma unroll
            for (int c = 0; c < 8; c++) {
                r[c] += __shfl_xor(r[c], 4);
                r[c] += __shfl_xor(r[c], 8);
            }
            if (g == 0 && l16 < 4) {
                float* po = (float*)out + (size_t)n * 32 + l16 * 8;
                *(float4*)po = make_float4(0.25f * r[0], 0.25f * r[1], 0.25f * r[2], 0.25f * r[3]);
                *(float4*)(po + 4) = make_float4(0.25f * r[4], 0.25f * r[5], 0.25f * r[6], 0.25f * r[7]);
            }
        }
    }
}

extern "C" void kernel_launch(void* const* d_in, const int* in_sizes, int n_in,
                              void* d_out, int out_size, void* d_ws, size_t ws_size,
                              hipStream_t stream) {
    const float* feat = (const float*)d_in[0];
    const int* src = (const int*)d_in[1];
    const int* dst = (const int*)d_in[2];
    const float* W1 = (const float*)d_in[3];
    const float* al1 = (const float*)d_in[4];
    const float* ar1 = (const float*)d_in[5];
    const float* b1 = (const float*)d_in[6];
    const float* W2 = (const float*)d_in[7];
    const float* al2 = (const float*)d_in[8];
    const float* ar2 = (const float*)d_in[9];
    const float* b2 = (const float*)d_in[10];
    float* out = (float*)d_out;

    char* ws = (char*)d_ws;
    size_t off = 0;
    auto alloc = [&](size_t bytes) {
        void* p = ws + off;
        off += (bytes + 255) & ~(size_t)255;
        return p;
    };
    int* deg = (int*)alloc((size_t)N_NODES * 4);
    int* done = (int*)alloc(256);                       // contiguous after deg -> one memset
    int* rs = (int*)alloc(((size_t)N_NODES + 1) * 4);   // +1 sentinel
    int* cursor = (int*)alloc((size_t)N_NODES * 4);
    int* bsums = (int*)alloc(128 * 4);
    int* csr_src = (int*)alloc((size_t)N_EDGES * 4);
    unsigned* Hb = (unsigned*)alloc((size_t)N_NODES * 64 * 4);     // bf16 H pairs
    float* el = (float*)alloc((size_t)N_NODES * 4 * 4);
    float* er = (float*)alloc((size_t)N_NODES * 4 * 4);
    unsigned* out1b = (unsigned*)alloc((size_t)N_NODES * 64 * 4);  // bf16 relu(out1)
    unsigned short* wt1 = (unsigned short*)alloc(128 * 128 * 2);
    unsigned short* wt2 = (unsigned short*)alloc(128 * 128 * 2);

    size_t zbytes = (size_t)((char*)done - (char*)deg) + 256;      // deg + done
    hipMemsetAsync(deg, 0, zbytes, stream);

    k_hist_wprep<<<3125 + 128, 256, 0, stream>>>(dst, deg, W1, W2, wt1, wt2);
    k_scan<<<98, 256, 0, stream>>>(deg, rs, cursor, bsums, done);
    k_scatter<<<(N_EDGES + 255) / 256, 256, 0, stream>>>(src, dst, cursor, csr_src);

    int gemm_blocks = (N_NODES + 127) / 128;
    int gat_blocks = (N_NODES + 15) / 16;   // 4 waves/block, 4 nodes/wave

    // layer 1
    k_gemm<<<gemm_blocks, 256, 0, stream>>>(feat, wt1, al1, ar1, Hb, el, er, 0);
    k_gather<<<gat_blocks, 256, 0, stream>>>(rs, csr_src, el, er, Hb, b1, out1b, 0);
    // layer 2
    k_gemm<<<gemm_blocks, 256, 0, stream>>>(out1b, wt2, al2, ar2, Hb, el, er, 1);
    k_gather<<<gat_blocks, 256, 0, stream>>>(rs, csr_src, el, er, Hb, b2, out, 1);
}

// Round 7
// 344.838 us; speedup vs baseline: 1.0525x; 1.0525x over previous
//
#include <hip/hip_runtime.h>
#include <math.h>

#define N_NODES 100000
#define N_EDGES 800000
#define NEG_SLOPE 0.2f

typedef __attribute__((ext_vector_type(8))) short short8;
typedef __attribute__((ext_vector_type(4))) float floatx4;

__device__ __forceinline__ float lrelu(float x) { return x > 0.f ? x : NEG_SLOPE * x; }

__device__ __forceinline__ unsigned bf16_rne(float f) {
    unsigned u = __float_as_uint(f);
    return (u + 0x7fffu + ((u >> 16) & 1u)) >> 16;
}
__device__ __forceinline__ unsigned bfpack(float lo, float hi) {
    return bf16_rne(lo) | (bf16_rne(hi) << 16);
}
__device__ __forceinline__ float bflo(unsigned p) { return __uint_as_float(p << 16); }
__device__ __forceinline__ float bfhi(unsigned p) { return __uint_as_float(p & 0xffff0000u); }

// ---------------- hist (blocks 0..3124) + W-prep (blocks 3125..3252) ----------------
__global__ __launch_bounds__(256) void k_hist_wprep(const int* __restrict__ dst,
                                                    int* __restrict__ deg,
                                                    const float* __restrict__ W1,
                                                    const float* __restrict__ W2,
                                                    unsigned short* __restrict__ wt1,
                                                    unsigned short* __restrict__ wt2) {
    int b = blockIdx.x;
    if (b < 3125) {
        int e = b * 256 + threadIdx.x;
        if (e < N_EDGES) atomicAdd(&deg[dst[e]], 1);
    } else {
        int tid = (b - 3125) * 256 + threadIdx.x;   // 0..32767
        const float* W = (tid < 16384) ? W1 : W2;
        unsigned short* wt = (tid < 16384) ? wt1 : wt2;
        int t = tid & 16383;
        int n = t >> 7, k = t & 127;
        wt[t] = (unsigned short)bf16_rne(W[k * 128 + n]);
    }
}

// ---------------- single-dispatch exclusive scan over deg (98 blocks, spin-sync) ----------------
__global__ __launch_bounds__(256) void k_scan(const int* __restrict__ deg,
                                              int* __restrict__ rs,
                                              int* __restrict__ cursor,
                                              int* __restrict__ bsums,
                                              int* __restrict__ done) {
    __shared__ int sd[256];
    int tid = threadIdx.x, b = blockIdx.x;
    int base = b * 1024 + tid * 4;
    int v0 = (base + 0 < N_NODES) ? deg[base + 0] : 0;
    int v1 = (base + 1 < N_NODES) ? deg[base + 1] : 0;
    int v2 = (base + 2 < N_NODES) ? deg[base + 2] : 0;
    int v3 = (base + 3 < N_NODES) ? deg[base + 3] : 0;
    int t = v0 + v1 + v2 + v3;
    sd[tid] = t;
    __syncthreads();
    int incl = t;
    for (int off = 1; off < 256; off <<= 1) {
        int x = (tid >= off) ? sd[tid - off] : 0;
        __syncthreads();
        incl += x;
        sd[tid] = incl;
        __syncthreads();
    }
    int excl = incl - t;

    if (tid == 255) {
        atomicExch(&bsums[b], incl);
        __threadfence();
        atomicAdd(done, 1);
    }
    if (tid == 0) {
        while (atomicAdd(done, 0) < 98) { }
    }
    __syncthreads();

    int bv = (tid < b) ? atomicAdd(&bsums[tid], 0) : 0;
    __syncthreads();
    sd[tid] = bv;
    __syncthreads();
    for (int off = 128; off > 0; off >>= 1) {
        if (tid < off) sd[tid] += sd[tid + off];
        __syncthreads();
    }
    int boff = sd[0];

    int p0 = excl + boff;
    if (base + 0 < N_NODES) { rs[base + 0] = p0; cursor[base + 0] = p0; }
    if (base + 1 < N_NODES) { rs[base + 1] = p0 + v0; cursor[base + 1] = p0 + v0; }
    if (base + 2 < N_NODES) { rs[base + 2] = p0 + v0 + v1; cursor[base + 2] = p0 + v0 + v1; }
    if (base + 3 < N_NODES) { rs[base + 3] = p0 + v0 + v1 + v2; cursor[base + 3] = p0 + v0 + v1 + v2; }
    if (b == 0 && tid == 0) rs[N_NODES] = N_EDGES;
}

__global__ void k_scatter(const int* __restrict__ src, const int* __restrict__ dst,
                          int* __restrict__ cursor, int* __restrict__ csr_src) {
    int e = blockIdx.x * blockDim.x + threadIdx.x;
    if (e < N_EDGES) {
        int d = dst[e];
        int p = atomicAdd(&cursor[d], 1);
        csr_src[p] = src[e];
    }
}

// ---------------- MFMA GEMM v2: coalesced LDS staging for BOTH tiles ----------------
// Block tile 128x128. wsh: swizzled W^T (32 KB). xsh: swizzled X tile (32 KB), staged
// with fully-coalesced global loads (wave covers 1-2 KB contiguous per instruction).
// Swizzle: chunk (kc,q) of row r stored at ((kc ^ ((r>>2)&3))*4 + (q ^ (r&3)))*8 shorts;
// both stage-writes and frag-reads land 2-way-max on banks (free, m136).
__global__ __launch_bounds__(256) void k_gemm(const void* __restrict__ Xv,
                                              const unsigned short* __restrict__ wt,
                                              const float* __restrict__ al,
                                              const float* __restrict__ ar,
                                              unsigned* __restrict__ Hb,
                                              float* __restrict__ EL,
                                              float* __restrict__ ER,
                                              int src_bf16) {
    __shared__ unsigned short wsh[128 * 128];   // 32 KB
    __shared__ unsigned short xsh[128 * 128];   // 32 KB
    int tid = threadIdx.x;
    int w = tid >> 6, lane = tid & 63;
    int q = lane >> 4, nl = lane & 15;
    int base = blockIdx.x * 128;

    // stage W
    const uint4* wt4 = (const uint4*)wt;
    #pragma unroll
    for (int i = 0; i < 8; i++) {
        int idx = tid + i * 256;                // 0..2047 chunks of 8 shorts
        int rn = idx >> 4, c8 = idx & 15;
        int kc = c8 >> 2, qq = c8 & 3;
        int slot = rn * 128 + ((kc ^ ((rn >> 2) & 3)) * 4 + (qq ^ (rn & 3))) * 8;
        *(uint4*)&wsh[slot] = wt4[idx];
    }

    // stage X (coalesced)
    if (!src_bf16) {
        const float4* X4 = (const float4*)Xv;
        #pragma unroll
        for (int i = 0; i < 8; i++) {
            int idx = tid + i * 256;            // 0..2047 chunks of 8 shorts
            int rn = idx >> 4, c8 = idx & 15;
            int rr = base + rn; if (rr >= N_NODES) rr = N_NODES - 1;
            float4 a = X4[(size_t)rr * 32 + c8 * 2];
            float4 bb = X4[(size_t)rr * 32 + c8 * 2 + 1];
            int kc = c8 >> 2, qq = c8 & 3;
            int slot = rn * 128 + ((kc ^ ((rn >> 2) & 3)) * 4 + (qq ^ (rn & 3))) * 8;
            uint4 pk;
            pk.x = bfpack(a.x, a.y); pk.y = bfpack(a.z, a.w);
            pk.z = bfpack(bb.x, bb.y); pk.w = bfpack(bb.z, bb.w);
            *(uint4*)&xsh[slot] = pk;
        }
    } else {
        const uint4* Xb4 = (const uint4*)Xv;
        #pragma unroll
        for (int i = 0; i < 8; i++) {
            int idx = tid + i * 256;
            int rn = idx >> 4, c8 = idx & 15;
            int rr = base + rn; if (rr >= N_NODES) rr = N_NODES - 1;
            int kc = c8 >> 2, qq = c8 & 3;
            int slot = rn * 128 + ((kc ^ ((rn >> 2) & 3)) * 4 + (qq ^ (rn & 3))) * 8;
            *(uint4*)&xsh[slot] = Xb4[(size_t)rr * 16 + c8];
        }
    }

    __syncthreads();

    int sw_hi = (nl >> 2) & 3, sw_lo = nl & 3;

    // A frags from LDS
    short8 afr[2][4];
    #pragma unroll
    for (int rt = 0; rt < 2; rt++) {
        int r = w * 32 + rt * 16 + nl;
        #pragma unroll
        for (int kc = 0; kc < 4; kc++)
            afr[rt][kc] = *(const short8*)&xsh[r * 128 + ((kc ^ sw_hi) * 4 + (q ^ sw_lo)) * 8];
    }

    floatx4 acc[2][8];
    #pragma unroll
    for (int rt = 0; rt < 2; rt++)
        #pragma unroll
        for (int ct = 0; ct < 8; ct++)
            acc[rt][ct] = (floatx4){0.f, 0.f, 0.f, 0.f};

    #pragma unroll
    for (int ct = 0; ct < 8; ct++) {
        int rbase = (ct * 16 + nl) * 128;
        #pragma unroll
        for (int kc = 0; kc < 4; kc++) {
            short8 b = *(const short8*)&wsh[rbase + ((kc ^ sw_hi) * 4 + (q ^ sw_lo)) * 8];
            acc[0][ct] = __builtin_amdgcn_mfma_f32_16x16x32_bf16(afr[0][kc], b, acc[0][ct], 0, 0, 0);
            acc[1][ct] = __builtin_amdgcn_mfma_f32_16x16x32_bf16(afr[1][kc], b, acc[1][ct], 0, 0, 0);
        }
    }

    float all_[4], alh_[4], arl_[4], arh_[4];
    #pragma unroll
    for (int h = 0; h < 4; h++) {
        all_[h] = al[h * 32 + nl]; alh_[h] = al[h * 32 + 16 + nl];
        arl_[h] = ar[h * 32 + nl]; arh_[h] = ar[h * 32 + 16 + nl];
    }
    #pragma unroll
    for (int rt = 0; rt < 2; rt++) {
        #pragma unroll
        for (int r = 0; r < 4; r++) {
            int row = base + w * 32 + rt * 16 + q * 4 + r;
            bool valid = row < N_NODES;
            unsigned* hrow = Hb + (size_t)row * 64;
            #pragma unroll
            for (int ct = 0; ct < 8; ct++) {
                float vlo = acc[rt][ct][r];
                float vhi = __shfl_down(vlo, 1);
                if (valid && !(nl & 1)) hrow[ct * 8 + (nl >> 1)] = bfpack(vlo, vhi);
            }
            #pragma unroll
            for (int h = 0; h < 4; h++) {
                float pel = acc[rt][2 * h][r] * all_[h] + acc[rt][2 * h + 1][r] * alh_[h];
                float per = acc[rt][2 * h][r] * arl_[h] + acc[rt][2 * h + 1][r] * arh_[h];
                #pragma unroll
                for (int o = 1; o < 16; o <<= 1) {
                    pel += __shfl_xor(pel, o);
                    per += __shfl_xor(per, o);
                }
                if (valid && nl == 0) { EL[row * 4 + h] = pel; ER[row * 4 + h] = per; }
            }
        }
    }
}

// ---------------- gather v3 (reverted from v4): fused softmax + aggregate ----------------
// One wave = 4 nodes sequential. 16 lanes/edge (uint4 = full 256B H row); 4 groups x 2
// batches = 8 edges per iteration. Low VGPR (28) -> high occupancy; TLP > ILP here
// (round-6 pipelined variant: 44 VGPR, occ 41%, REGRESSED 55->61 us).
__global__ __launch_bounds__(256) void k_gather(const int* __restrict__ rs,
                                                const int* __restrict__ csr_src,
                                                const float* __restrict__ EL,
                                                const float* __restrict__ ER,
                                                const unsigned* __restrict__ Hb,
                                                const float* __restrict__ bias,
                                                void* __restrict__ out,
                                                int final_layer) {
    int wid = (blockIdx.x * blockDim.x + threadIdx.x) >> 6;
    int lane = threadIdx.x & 63;
    int g = lane >> 4, l16 = lane & 15;
    int h = l16 >> 2;
    int n0 = wid * 4;
    if (n0 >= N_NODES) return;
    int nend = min(n0 + 4, N_NODES);

    float bv[8];
    #pragma unroll
    for (int c = 0; c < 8; c++) bv[c] = bias[l16 * 8 + c];

    for (int n = n0; n < nend; n++) {
        int s = rs[n], e = rs[n + 1];
        float erh = ER[n * 4 + h];
        float acc[8];
        #pragma unroll
        for (int c = 0; c < 8; c++) acc[c] = 0.f;
        float sa = 0.f;

        for (int j = s; j < e; j += 8) {
            int j0 = j + g, j1 = j + 4 + g;
            uint4 p0 = make_uint4(0, 0, 0, 0), p1 = make_uint4(0, 0, 0, 0);
            float w0 = 0.f, w1 = 0.f;
            if (j0 < e) {
                int s0 = csr_src[j0];
                p0 = *(const uint4*)(Hb + (size_t)s0 * 64 + l16 * 4);
                w0 = __expf(lrelu(EL[s0 * 4 + h] + erh));
            }
            if (j1 < e) {
                int s1 = csr_src[j1];
                p1 = *(const uint4*)(Hb + (size_t)s1 * 64 + l16 * 4);
                w1 = __expf(lrelu(EL[s1 * 4 + h] + erh));
            }
            sa += w0 + w1;
            acc[0] = fmaf(bflo(p0.x), w0, acc[0]); acc[1] = fmaf(bfhi(p0.x), w0, acc[1]);
            acc[2] = fmaf(bflo(p0.y), w0, acc[2]); acc[3] = fmaf(bfhi(p0.y), w0, acc[3]);
            acc[4] = fmaf(bflo(p0.z), w0, acc[4]); acc[5] = fmaf(bfhi(p0.z), w0, acc[5]);
            acc[6] = fmaf(bflo(p0.w), w0, acc[6]); acc[7] = fmaf(bfhi(p0.w), w0, acc[7]);
            acc[0] = fmaf(bflo(p1.x), w1, acc[0]); acc[1] = fmaf(bfhi(p1.x), w1, acc[1]);
            acc[2] = fmaf(bflo(p1.y), w1, acc[2]); acc[3] = fmaf(bfhi(p1.y), w1, acc[3]);
            acc[4] = fmaf(bflo(p1.z), w1, acc[4]); acc[5] = fmaf(bfhi(p1.z), w1, acc[5]);
            acc[6] = fmaf(bflo(p1.w), w1, acc[6]); acc[7] = fmaf(bfhi(p1.w), w1, acc[7]);
        }

        #pragma unroll
        for (int c = 0; c < 8; c++) {
            acc[c] += __shfl_xor(acc[c], 16);
            acc[c] += __shfl_xor(acc[c], 32);
        }
        sa += __shfl_xor(sa, 16);
        sa += __shfl_xor(sa, 32);
        float inv = (e > s) ? 1.f / sa : 0.f;

        float r[8];
        #pragma unroll
        for (int c = 0; c < 8; c++) r[c] = acc[c] * inv + bv[c];

        if (!final_layer) {
            if (g == 0) {
                uint4 pk;
                pk.x = bfpack(fmaxf(r[0], 0.f), fmaxf(r[1], 0.f));
                pk.y = bfpack(fmaxf(r[2], 0.f), fmaxf(r[3], 0.f));
                pk.z = bfpack(fmaxf(r[4], 0.f), fmaxf(r[5], 0.f));
                pk.w = bfpack(fmaxf(r[6], 0.f), fmaxf(r[7], 0.f));
                *(uint4*)((unsigned*)out + (size_t)n * 64 + l16 * 4) = pk;
            }
        } else {
            #pragma unroll
            for (int c = 0; c < 8; c++) {
                r[c] += __shfl_xor(r[c], 4);
                r[c] += __shfl_xor(r[c], 8);
            }
            if (g == 0 && l16 < 4) {
                float* po = (float*)out + (size_t)n * 32 + l16 * 8;
                *(float4*)po = make_float4(0.25f * r[0], 0.25f * r[1], 0.25f * r[2], 0.25f * r[3]);
                *(float4*)(po + 4) = make_float4(0.25f * r[4], 0.25f * r[5], 0.25f * r[6], 0.25f * r[7]);
            }
        }
    }
}

extern "C" void kernel_launch(void* const* d_in, const int* in_sizes, int n_in,
                              void* d_out, int out_size, void* d_ws, size_t ws_size,
                              hipStream_t stream) {
    const float* feat = (const float*)d_in[0];
    const int* src = (const int*)d_in[1];
    const int* dst = (const int*)d_in[2];
    const float* W1 = (const float*)d_in[3];
    const float* al1 = (const float*)d_in[4];
    const float* ar1 = (const float*)d_in[5];
    const float* b1 = (const float*)d_in[6];
    const float* W2 = (const float*)d_in[7];
    const float* al2 = (const float*)d_in[8];
    const float* ar2 = (const float*)d_in[9];
    const float* b2 = (const float*)d_in[10];
    float* out = (float*)d_out;

    char* ws = (char*)d_ws;
    size_t off = 0;
    auto alloc = [&](size_t bytes) {
        void* p = ws + off;
        off += (bytes + 255) & ~(size_t)255;
        return p;
    };
    int* deg = (int*)alloc((size_t)N_NODES * 4);
    int* done = (int*)alloc(256);                       // contiguous after deg -> one memset
    int* rs = (int*)alloc(((size_t)N_NODES + 1) * 4);   // +1 sentinel
    int* cursor = (int*)alloc((size_t)N_NODES * 4);
    int* bsums = (int*)alloc(128 * 4);
    int* csr_src = (int*)alloc((size_t)N_EDGES * 4);
    unsigned* Hb = (unsigned*)alloc((size_t)N_NODES * 64 * 4);     // bf16 H pairs
    float* el = (float*)alloc((size_t)N_NODES * 4 * 4);
    float* er = (float*)alloc((size_t)N_NODES * 4 * 4);
    unsigned* out1b = (unsigned*)alloc((size_t)N_NODES * 64 * 4);  // bf16 relu(out1)
    unsigned short* wt1 = (unsigned short*)alloc(128 * 128 * 2);
    unsigned short* wt2 = (unsigned short*)alloc(128 * 128 * 2);

    size_t zbytes = (size_t)((char*)done - (char*)deg) + 256;
    hipMemsetAsync(deg, 0, zbytes, stream);

    k_hist_wprep<<<3125 + 128, 256, 0, stream>>>(dst, deg, W1, W2, wt1, wt2);
    k_scan<<<98, 256, 0, stream>>>(deg, rs, cursor, bsums, done);
    k_scatter<<<(N_EDGES + 255) / 256, 256, 0, stream>>>(src, dst, cursor, csr_src);

    int gemm_blocks = (N_NODES + 127) / 128;
    int gat_blocks = (N_NODES + 15) / 16;   // 4 waves/block, 4 nodes/wave

    // layer 1
    k_gemm<<<gemm_blocks, 256, 0, stream>>>(feat, wt1, al1, ar1, Hb, el, er, 0);
    k_gather<<<gat_blocks, 256, 0, stream>>>(rs, csr_src, el, er, Hb, b1, out1b, 0);
    // layer 2
    k_gemm<<<gemm_blocks, 256, 0, stream>>>(out1b, wt2, al2, ar2, Hb, el, er, 1);
    k_gather<<<gat_blocks, 256, 0, stream>>>(rs, csr_src, el, er, Hb, b2, out, 1);
}

// Round 8
// 330.802 us; speedup vs baseline: 1.0971x; 1.0424x over previous
//
#include <hip/hip_runtime.h>
#include <math.h>

#define N_NODES 100000
#define N_EDGES 800000
#define NEG_SLOPE 0.2f
#define NB_CSR 98
#define NT_CSR (NB_CSR * 256)

typedef __attribute__((ext_vector_type(8))) short short8;
typedef __attribute__((ext_vector_type(4))) float floatx4;

__device__ __forceinline__ float lrelu(float x) { return x > 0.f ? x : NEG_SLOPE * x; }

__device__ __forceinline__ unsigned bf16_rne(float f) {
    unsigned u = __float_as_uint(f);
    return (u + 0x7fffu + ((u >> 16) & 1u)) >> 16;
}
__device__ __forceinline__ unsigned bfpack(float lo, float hi) {
    return bf16_rne(lo) | (bf16_rne(hi) << 16);
}
__device__ __forceinline__ float bflo(unsigned p) { return __uint_as_float(p << 16); }
__device__ __forceinline__ float bfhi(unsigned p) { return __uint_as_float(p & 0xffff0000u); }

__device__ __forceinline__ void gbar(int* ctr) {
    __syncthreads();
    if (threadIdx.x == 0) {
        __threadfence();
        atomicAdd(ctr, 1);
        while (atomicAdd(ctr, 0) < NB_CSR) { }
    }
    __syncthreads();
}

// ---------------- fused prep: CSR build (blocks 0..97) + W transpose (98..225)
//                  + E = [W al | W ar] (226..227) ----------------
__global__ __launch_bounds__(256) void k_pre(const int* __restrict__ src,
                                             const int* __restrict__ dst,
                                             int* __restrict__ deg,
                                             int* __restrict__ rs,
                                             int* __restrict__ cursor,
                                             int* __restrict__ bsums,
                                             int* __restrict__ done,
                                             int* __restrict__ csr_src,
                                             const float* __restrict__ W1,
                                             const float* __restrict__ al1,
                                             const float* __restrict__ ar1,
                                             const float* __restrict__ W2,
                                             const float* __restrict__ al2,
                                             const float* __restrict__ ar2,
                                             unsigned short* __restrict__ wt1,
                                             unsigned short* __restrict__ wt2,
                                             unsigned short* __restrict__ et1,
                                             unsigned short* __restrict__ et2) {
    int b = blockIdx.x, tid = threadIdx.x;
    if (b >= NB_CSR) {
        int wb = b - NB_CSR;
        if (wb < 128) {
            // W^T + bf16
            int t2 = wb * 256 + tid;              // 0..32767
            const float* W = (t2 < 16384) ? W1 : W2;
            unsigned short* wt = (t2 < 16384) ? wt1 : wt2;
            int t = t2 & 16383;
            int n = t >> 7, k = t & 127;
            wt[t] = (unsigned short)bf16_rne(W[k * 128 + n]);
        } else {
            // E[n][k]: n<4 -> (W al)_head n ; 4<=n<8 -> (W ar)_head n-4 ; else 0
            const float* W = (wb == 128) ? W1 : W2;
            const float* al = (wb == 128) ? al1 : al2;
            const float* ar = (wb == 128) ? ar1 : ar2;
            unsigned short* et = (wb == 128) ? et1 : et2;
            for (int o = tid * 8; o < tid * 8 + 8; o++) {   // 2048 outputs
                int n = o >> 7, k = o & 127;
                float sacc = 0.f;
                if (n < 8) {
                    const float* a = (n < 4) ? al : ar;
                    int hh = n & 3;
                    #pragma unroll 8
                    for (int c = 0; c < 32; c++)
                        sacc += W[k * 128 + hh * 32 + c] * a[hh * 32 + c];
                }
                et[n * 128 + k] = (unsigned short)bf16_rne(sacc);
            }
        }
        return;
    }

    // ---- CSR blocks: zero -> hist -> scan -> scatter, spin-barriered ----
    int gtid = b * 256 + tid;
    // phase 0: zero deg
    for (int i = gtid; i < N_NODES; i += NT_CSR) deg[i] = 0;
    gbar(&done[0]);
    // phase 1: histogram
    for (int e = gtid; e < N_EDGES; e += NT_CSR) atomicAdd(&deg[dst[e]], 1);
    gbar(&done[1]);
    // phase 2: exclusive scan (block b owns nodes b*1024..+1023)
    __shared__ int sd[256];
    int base = b * 1024 + tid * 4;
    int v0 = (base + 0 < N_NODES) ? atomicAdd(&deg[base + 0], 0) : 0;
    int v1 = (base + 1 < N_NODES) ? atomicAdd(&deg[base + 1], 0) : 0;
    int v2 = (base + 2 < N_NODES) ? atomicAdd(&deg[base + 2], 0) : 0;
    int v3 = (base + 3 < N_NODES) ? atomicAdd(&deg[base + 3], 0) : 0;
    int t = v0 + v1 + v2 + v3;
    sd[tid] = t;
    __syncthreads();
    int incl = t;
    for (int off = 1; off < 256; off <<= 1) {
        int x = (tid >= off) ? sd[tid - off] : 0;
        __syncthreads();
        incl += x;
        sd[tid] = incl;
        __syncthreads();
    }
    int excl = incl - t;

    if (tid == 255) {
        atomicExch(&bsums[b], incl);
        __threadfence();
        atomicAdd(&done[2], 1);
    }
    if (tid == 0) {
        while (atomicAdd(&done[2], 0) < NB_CSR) { }
    }
    __syncthreads();

    int bv = (tid < b) ? atomicAdd(&bsums[tid], 0) : 0;
    __syncthreads();
    sd[tid] = bv;
    __syncthreads();
    for (int off = 128; off > 0; off >>= 1) {
        if (tid < off) sd[tid] += sd[tid + off];
        __syncthreads();
    }
    int boff = sd[0];

    int p0 = excl + boff;
    if (base + 0 < N_NODES) { rs[base + 0] = p0; cursor[base + 0] = p0; }
    if (base + 1 < N_NODES) { rs[base + 1] = p0 + v0; cursor[base + 1] = p0 + v0; }
    if (base + 2 < N_NODES) { rs[base + 2] = p0 + v0 + v1; cursor[base + 2] = p0 + v0 + v1; }
    if (base + 3 < N_NODES) { rs[base + 3] = p0 + v0 + v1 + v2; cursor[base + 3] = p0 + v0 + v1 + v2; }
    if (b == 0 && tid == 0) rs[N_NODES] = N_EDGES;
    gbar(&done[3]);
    // phase 3: scatter
    for (int e = gtid; e < N_EDGES; e += NT_CSR) {
        int d = dst[e];
        int p = atomicAdd(&cursor[d], 1);
        csr_src[p] = src[e];
    }
}

// ---------------- MFMA GEMM v3: direct-global A frags, W in LDS, el/er via MFMA ----------------
// 782 blocks x 4 waves; block tile 128 rows x (128 H-cols + 8 E-cols).
// E-cols: el[row][h] = (X (W al))[row][h] -> 8 extra MFMAs replace 256 epilogue shuffles.
__global__ __launch_bounds__(256) void k_gemm(const void* __restrict__ Xv,
                                              const unsigned short* __restrict__ wt,
                                              const unsigned short* __restrict__ et,
                                              unsigned* __restrict__ Hb,
                                              float* __restrict__ EL,
                                              float* __restrict__ ER,
                                              int src_bf16) {
    __shared__ unsigned short wsh[128 * 128];   // 32 KB, swizzled [n][k] bf16
    __shared__ unsigned short esh[16 * 136];    // padded E tile (stride 136 shorts)
    int tid = threadIdx.x;
    int w = tid >> 6, lane = tid & 63;
    int q = lane >> 4, nl = lane & 15;
    int base = blockIdx.x * 128;

    const uint4* wt4 = (const uint4*)wt;
    #pragma unroll
    for (int i = 0; i < 8; i++) {
        int idx = tid + i * 256;                // 0..2047 chunks of 8 shorts
        int rn = idx >> 4, c8 = idx & 15;
        int kc = c8 >> 2, qq = c8 & 3;
        int slot = rn * 128 + ((kc ^ ((rn >> 2) & 3)) * 4 + (qq ^ (rn & 3))) * 8;
        *(uint4*)&wsh[slot] = wt4[idx];
    }
    {   // stage E tile: 2048 shorts, one uint4 per thread, +8-short row pad
        const uint4* et4 = (const uint4*)et;
        int rn = tid >> 4, c8 = tid & 15;
        *(uint4*)&esh[rn * 136 + c8 * 8] = et4[tid];
    }

    // A fragments: A[m=nl][k=q*8+j], rows w*32 + rt*16 + nl (direct from global)
    short8 afr[2][4];
    int row0 = base + w * 32 + nl;
    if (!src_bf16) {
        const float4* X4 = (const float4*)Xv;
        #pragma unroll
        for (int rt = 0; rt < 2; rt++) {
            int rr = row0 + rt * 16; if (rr > N_NODES - 1) rr = N_NODES - 1;
            const float4* px = X4 + (size_t)rr * 32 + q * 2;
            #pragma unroll
            for (int kc = 0; kc < 4; kc++) {
                float4 u = px[kc * 8], v = px[kc * 8 + 1];
                short8 f;
                f[0] = (short)bf16_rne(u.x); f[1] = (short)bf16_rne(u.y);
                f[2] = (short)bf16_rne(u.z); f[3] = (short)bf16_rne(u.w);
                f[4] = (short)bf16_rne(v.x); f[5] = (short)bf16_rne(v.y);
                f[6] = (short)bf16_rne(v.z); f[7] = (short)bf16_rne(v.w);
                afr[rt][kc] = f;
            }
        }
    } else {
        const unsigned short* Xb = (const unsigned short*)Xv;
        #pragma unroll
        for (int rt = 0; rt < 2; rt++) {
            int rr = row0 + rt * 16; if (rr > N_NODES - 1) rr = N_NODES - 1;
            #pragma unroll
            for (int kc = 0; kc < 4; kc++)
                afr[rt][kc] = *(const short8*)(Xb + (size_t)rr * 128 + kc * 32 + q * 8);
        }
    }

    floatx4 acc[2][8];
    floatx4 acc_e[2];
    #pragma unroll
    for (int rt = 0; rt < 2; rt++) {
        acc_e[rt] = (floatx4){0.f, 0.f, 0.f, 0.f};
        #pragma unroll
        for (int ct = 0; ct < 8; ct++)
            acc[rt][ct] = (floatx4){0.f, 0.f, 0.f, 0.f};
    }

    __syncthreads();

    int sw_hi = (nl >> 2) & 3, sw_lo = nl & 3;
    #pragma unroll
    for (int ct = 0; ct < 8; ct++) {
        int rbase = (ct * 16 + nl) * 128;
        #pragma unroll
        for (int kc = 0; kc < 4; kc++) {
            short8 b = *(const short8*)&wsh[rbase + ((kc ^ sw_hi) * 4 + (q ^ sw_lo)) * 8];
            acc[0][ct] = __builtin_amdgcn_mfma_f32_16x16x32_bf16(afr[0][kc], b, acc[0][ct], 0, 0, 0);
            acc[1][ct] = __builtin_amdgcn_mfma_f32_16x16x32_bf16(afr[1][kc], b, acc[1][ct], 0, 0, 0);
        }
    }
    // E columns (el heads 0..3, er heads 4..7)
    #pragma unroll
    for (int kc = 0; kc < 4; kc++) {
        short8 e8 = *(const short8*)&esh[nl * 136 + (kc * 4 + q) * 8];
        acc_e[0] = __builtin_amdgcn_mfma_f32_16x16x32_bf16(afr[0][kc], e8, acc_e[0], 0, 0, 0);
        acc_e[1] = __builtin_amdgcn_mfma_f32_16x16x32_bf16(afr[1][kc], e8, acc_e[1], 0, 0, 0);
    }

    // epilogue: bf16 H pack (64 shfl_down) + direct EL/ER stores
    #pragma unroll
    for (int rt = 0; rt < 2; rt++) {
        #pragma unroll
        for (int r = 0; r < 4; r++) {
            int row = base + w * 32 + rt * 16 + q * 4 + r;
            bool valid = row < N_NODES;
            unsigned* hrow = Hb + (size_t)row * 64;
            #pragma unroll
            for (int ct = 0; ct < 8; ct++) {
                float vlo = acc[rt][ct][r];
                float vhi = __shfl_down(vlo, 1);
                if (valid && !(nl & 1)) hrow[ct * 8 + (nl >> 1)] = bfpack(vlo, vhi);
            }
            if (valid && nl < 8) {
                float v = acc_e[rt][r];
                if (nl < 4) EL[row * 4 + nl] = v;
                else        ER[row * 4 + (nl & 3)] = v;
            }
        }
    }
}

// ---------------- gather v3: fused softmax + aggregate (kept from round 7) ----------------
__global__ __launch_bounds__(256) void k_gather(const int* __restrict__ rs,
                                                const int* __restrict__ csr_src,
                                                const float* __restrict__ EL,
                                                const float* __restrict__ ER,
                                                const unsigned* __restrict__ Hb,
                                                const float* __restrict__ bias,
                                                void* __restrict__ out,
                                                int final_layer) {
    int wid = (blockIdx.x * blockDim.x + threadIdx.x) >> 6;
    int lane = threadIdx.x & 63;
    int g = lane >> 4, l16 = lane & 15;
    int h = l16 >> 2;
    int n0 = wid * 4;
    if (n0 >= N_NODES) return;
    int nend = min(n0 + 4, N_NODES);

    float bv[8];
    #pragma unroll
    for (int c = 0; c < 8; c++) bv[c] = bias[l16 * 8 + c];

    for (int n = n0; n < nend; n++) {
        int s = rs[n], e = rs[n + 1];
        float erh = ER[n * 4 + h];
        float acc[8];
        #pragma unroll
        for (int c = 0; c < 8; c++) acc[c] = 0.f;
        float sa = 0.f;

        for (int j = s; j < e; j += 8) {
            int j0 = j + g, j1 = j + 4 + g;
            uint4 p0 = make_uint4(0, 0, 0, 0), p1 = make_uint4(0, 0, 0, 0);
            float w0 = 0.f, w1 = 0.f;
            if (j0 < e) {
                int s0 = csr_src[j0];
                p0 = *(const uint4*)(Hb + (size_t)s0 * 64 + l16 * 4);
                w0 = __expf(lrelu(EL[s0 * 4 + h] + erh));
            }
            if (j1 < e) {
                int s1 = csr_src[j1];
                p1 = *(const uint4*)(Hb + (size_t)s1 * 64 + l16 * 4);
                w1 = __expf(lrelu(EL[s1 * 4 + h] + erh));
            }
            sa += w0 + w1;
            acc[0] = fmaf(bflo(p0.x), w0, acc[0]); acc[1] = fmaf(bfhi(p0.x), w0, acc[1]);
            acc[2] = fmaf(bflo(p0.y), w0, acc[2]); acc[3] = fmaf(bfhi(p0.y), w0, acc[3]);
            acc[4] = fmaf(bflo(p0.z), w0, acc[4]); acc[5] = fmaf(bfhi(p0.z), w0, acc[5]);
            acc[6] = fmaf(bflo(p0.w), w0, acc[6]); acc[7] = fmaf(bfhi(p0.w), w0, acc[7]);
            acc[0] = fmaf(bflo(p1.x), w1, acc[0]); acc[1] = fmaf(bfhi(p1.x), w1, acc[1]);
            acc[2] = fmaf(bflo(p1.y), w1, acc[2]); acc[3] = fmaf(bfhi(p1.y), w1, acc[3]);
            acc[4] = fmaf(bflo(p1.z), w1, acc[4]); acc[5] = fmaf(bfhi(p1.z), w1, acc[5]);
            acc[6] = fmaf(bflo(p1.w), w1, acc[6]); acc[7] = fmaf(bfhi(p1.w), w1, acc[7]);
        }

        #pragma unroll
        for (int c = 0; c < 8; c++) {
            acc[c] += __shfl_xor(acc[c], 16);
            acc[c] += __shfl_xor(acc[c], 32);
        }
        sa += __shfl_xor(sa, 16);
        sa += __shfl_xor(sa, 32);
        float inv = (e > s) ? 1.f / sa : 0.f;

        float r[8];
        #pragma unroll
        for (int c = 0; c < 8; c++) r[c] = acc[c] * inv + bv[c];

        if (!final_layer) {
            if (g == 0) {
                uint4 pk;
                pk.x = bfpack(fmaxf(r[0], 0.f), fmaxf(r[1], 0.f));
                pk.y = bfpack(fmaxf(r[2], 0.f), fmaxf(r[3], 0.f));
                pk.z = bfpack(fmaxf(r[4], 0.f), fmaxf(r[5], 0.f));
                pk.w = bfpack(fmaxf(r[6], 0.f), fmaxf(r[7], 0.f));
                *(uint4*)((unsigned*)out + (size_t)n * 64 + l16 * 4) = pk;
            }
        } else {
            #pragma unroll
            for (int c = 0; c < 8; c++) {
                r[c] += __shfl_xor(r[c], 4);
                r[c] += __shfl_xor(r[c], 8);
            }
            if (g == 0 && l16 < 4) {
                float* po = (float*)out + (size_t)n * 32 + l16 * 8;
                *(float4*)po = make_float4(0.25f * r[0], 0.25f * r[1], 0.25f * r[2], 0.25f * r[3]);
                *(float4*)(po + 4) = make_float4(0.25f * r[4], 0.25f * r[5], 0.25f * r[6], 0.25f * r[7]);
            }
        }
    }
}

extern "C" void kernel_launch(void* const* d_in, const int* in_sizes, int n_in,
                              void* d_out, int out_size, void* d_ws, size_t ws_size,
                              hipStream_t stream) {
    const float* feat = (const float*)d_in[0];
    const int* src = (const int*)d_in[1];
    const int* dst = (const int*)d_in[2];
    const float* W1 = (const float*)d_in[3];
    const float* al1 = (const float*)d_in[4];
    const float* ar1 = (const float*)d_in[5];
    const float* b1 = (const float*)d_in[6];
    const float* W2 = (const float*)d_in[7];
    const float* al2 = (const float*)d_in[8];
    const float* ar2 = (const float*)d_in[9];
    const float* b2 = (const float*)d_in[10];
    float* out = (float*)d_out;

    char* ws = (char*)d_ws;
    size_t off = 0;
    auto alloc = [&](size_t bytes) {
        void* p = ws + off;
        off += (bytes + 255) & ~(size_t)255;
        return p;
    };
    int* done = (int*)alloc(256);                       // barrier counters (memset'd)
    int* deg = (int*)alloc((size_t)N_NODES * 4);        // zeroed in-kernel
    int* rs = (int*)alloc(((size_t)N_NODES + 1) * 4);
    int* cursor = (int*)alloc((size_t)N_NODES * 4);
    int* bsums = (int*)alloc(128 * 4);
    int* csr_src = (int*)alloc((size_t)N_EDGES * 4);
    unsigned* Hb = (unsigned*)alloc((size_t)N_NODES * 64 * 4);     // bf16 H pairs
    float* el = (float*)alloc((size_t)N_NODES * 4 * 4);
    float* er = (float*)alloc((size_t)N_NODES * 4 * 4);
    unsigned* out1b = (unsigned*)alloc((size_t)N_NODES * 64 * 4);  // bf16 relu(out1)
    unsigned short* wt1 = (unsigned short*)alloc(128 * 128 * 2);
    unsigned short* wt2 = (unsigned short*)alloc(128 * 128 * 2);
    unsigned short* et1 = (unsigned short*)alloc(16 * 128 * 2);
    unsigned short* et2 = (unsigned short*)alloc(16 * 128 * 2);

    hipMemsetAsync(done, 0, 256, stream);

    k_pre<<<NB_CSR + 128 + 2, 256, 0, stream>>>(src, dst, deg, rs, cursor, bsums, done,
                                                csr_src, W1, al1, ar1, W2, al2, ar2,
                                                wt1, wt2, et1, et2);

    int gemm_blocks = (N_NODES + 127) / 128;
    int gat_blocks = (N_NODES + 15) / 16;

    // layer 1
    k_gemm<<<gemm_blocks, 256, 0, stream>>>(feat, wt1, et1, Hb, el, er, 0);
    k_gather<<<gat_blocks, 256, 0, stream>>>(rs, csr_src, el, er, Hb, b1, out1b, 0);
    // layer 2
    k_gemm<<<gemm_blocks, 256, 0, stream>>>(out1b, wt2, et2, Hb, el, er, 1);
    k_gather<<<gat_blocks, 256, 0, stream>>>(rs, csr_src, el, er, Hb, b2, out, 1);
}

// Round 9
// 330.105 us; speedup vs baseline: 1.0995x; 1.0021x over previous
//
#include <hip/hip_runtime.h>
#include <math.h>

#define N_NODES 100000
#define N_EDGES 800000
#define NEG_SLOPE 0.2f

typedef __attribute__((ext_vector_type(8))) short short8;
typedef __attribute__((ext_vector_type(4))) float floatx4;

__device__ __forceinline__ float lrelu(float x) { return x > 0.f ? x : NEG_SLOPE * x; }

__device__ __forceinline__ unsigned bf16_rne(float f) {
    unsigned u = __float_as_uint(f);
    return (u + 0x7fffu + ((u >> 16) & 1u)) >> 16;
}
__device__ __forceinline__ unsigned bfpack(float lo, float hi) {
    return bf16_rne(lo) | (bf16_rne(hi) << 16);
}
__device__ __forceinline__ float bflo(unsigned p) { return __uint_as_float(p << 16); }
__device__ __forceinline__ float bfhi(unsigned p) { return __uint_as_float(p & 0xffff0000u); }

// ---------------- hist (0..3124) + W^T (3125..3252) + E = [W al | W ar] (3253..3254) ----------------
__global__ __launch_bounds__(256) void k_hist_wprep(const int* __restrict__ dst,
                                                    int* __restrict__ deg,
                                                    const float* __restrict__ W1,
                                                    const float* __restrict__ al1,
                                                    const float* __restrict__ ar1,
                                                    const float* __restrict__ W2,
                                                    const float* __restrict__ al2,
                                                    const float* __restrict__ ar2,
                                                    unsigned short* __restrict__ wt1,
                                                    unsigned short* __restrict__ wt2,
                                                    unsigned short* __restrict__ et1,
                                                    unsigned short* __restrict__ et2) {
    int b = blockIdx.x, tid = threadIdx.x;
    if (b < 3125) {
        int e = b * 256 + tid;
        if (e < N_EDGES) atomicAdd(&deg[dst[e]], 1);
    } else if (b < 3253) {
        int t2 = (b - 3125) * 256 + tid;          // 0..32767
        const float* W = (t2 < 16384) ? W1 : W2;
        unsigned short* wt = (t2 < 16384) ? wt1 : wt2;
        int t = t2 & 16383;
        int n = t >> 7, k = t & 127;
        wt[t] = (unsigned short)bf16_rne(W[k * 128 + n]);
    } else {
        // E[n][k]: n<4 -> (W al)_head n ; 4<=n<8 -> (W ar)_head n-4 ; else 0
        const float* W = (b == 3253) ? W1 : W2;
        const float* al = (b == 3253) ? al1 : al2;
        const float* ar = (b == 3253) ? ar1 : ar2;
        unsigned short* et = (b == 3253) ? et1 : et2;
        for (int o = tid * 8; o < tid * 8 + 8; o++) {   // 2048 outputs
            int n = o >> 7, k = o & 127;
            float sacc = 0.f;
            if (n < 8) {
                const float* a = (n < 4) ? al : ar;
                int hh = n & 3;
                #pragma unroll 8
                for (int c = 0; c < 32; c++)
                    sacc += W[k * 128 + hh * 32 + c] * a[hh * 32 + c];
            }
            et[n * 128 + k] = (unsigned short)bf16_rne(sacc);
        }
    }
}

// ---------------- exclusive scan over deg (98 blocks, one spin-sync) ----------------
__global__ __launch_bounds__(256) void k_scan(const int* __restrict__ deg,
                                              int* __restrict__ rs,
                                              int* __restrict__ cursor,
                                              int* __restrict__ bsums,
                                              int* __restrict__ done) {
    __shared__ int sd[256];
    int tid = threadIdx.x, b = blockIdx.x;
    int base = b * 1024 + tid * 4;
    int v0 = (base + 0 < N_NODES) ? deg[base + 0] : 0;
    int v1 = (base + 1 < N_NODES) ? deg[base + 1] : 0;
    int v2 = (base + 2 < N_NODES) ? deg[base + 2] : 0;
    int v3 = (base + 3 < N_NODES) ? deg[base + 3] : 0;
    int t = v0 + v1 + v2 + v3;
    sd[tid] = t;
    __syncthreads();
    int incl = t;
    for (int off = 1; off < 256; off <<= 1) {
        int x = (tid >= off) ? sd[tid - off] : 0;
        __syncthreads();
        incl += x;
        sd[tid] = incl;
        __syncthreads();
    }
    int excl = incl - t;

    if (tid == 255) {
        atomicExch(&bsums[b], incl);
        __threadfence();
        atomicAdd(done, 1);
    }
    if (tid == 0) {
        while (atomicAdd(done, 0) < 98) { }
    }
    __syncthreads();

    int bv = (tid < b) ? atomicAdd(&bsums[tid], 0) : 0;
    __syncthreads();
    sd[tid] = bv;
    __syncthreads();
    for (int off = 128; off > 0; off >>= 1) {
        if (tid < off) sd[tid] += sd[tid + off];
        __syncthreads();
    }
    int boff = sd[0];

    int p0 = excl + boff;
    if (base + 0 < N_NODES) { rs[base + 0] = p0; cursor[base + 0] = p0; }
    if (base + 1 < N_NODES) { rs[base + 1] = p0 + v0; cursor[base + 1] = p0 + v0; }
    if (base + 2 < N_NODES) { rs[base + 2] = p0 + v0 + v1; cursor[base + 2] = p0 + v0 + v1; }
    if (base + 3 < N_NODES) { rs[base + 3] = p0 + v0 + v1 + v2; cursor[base + 3] = p0 + v0 + v1 + v2; }
    if (b == 0 && tid == 0) rs[N_NODES] = N_EDGES;
}

__global__ void k_scatter(const int* __restrict__ src, const int* __restrict__ dst,
                          int* __restrict__ cursor, int* __restrict__ csr_src) {
    int e = blockIdx.x * blockDim.x + threadIdx.x;
    if (e < N_EDGES) {
        int d = dst[e];
        int p = atomicAdd(&cursor[d], 1);
        csr_src[p] = src[e];
    }
}

// ---------------- MFMA GEMM v3: direct-global A frags, W in LDS, el/er via MFMA ----------------
__global__ __launch_bounds__(256) void k_gemm(const void* __restrict__ Xv,
                                              const unsigned short* __restrict__ wt,
                                              const unsigned short* __restrict__ et,
                                              unsigned* __restrict__ Hb,
                                              float* __restrict__ EL,
                                              float* __restrict__ ER,
                                              int src_bf16) {
    __shared__ unsigned short wsh[128 * 128];   // 32 KB, swizzled [n][k] bf16
    __shared__ unsigned short esh[16 * 136];    // padded E tile
    int tid = threadIdx.x;
    int w = tid >> 6, lane = tid & 63;
    int q = lane >> 4, nl = lane & 15;
    int base = blockIdx.x * 128;

    const uint4* wt4 = (const uint4*)wt;
    #pragma unroll
    for (int i = 0; i < 8; i++) {
        int idx = tid + i * 256;                // 0..2047 chunks of 8 shorts
        int rn = idx >> 4, c8 = idx & 15;
        int kc = c8 >> 2, qq = c8 & 3;
        int slot = rn * 128 + ((kc ^ ((rn >> 2) & 3)) * 4 + (qq ^ (rn & 3))) * 8;
        *(uint4*)&wsh[slot] = wt4[idx];
    }
    {
        const uint4* et4 = (const uint4*)et;
        int rn = tid >> 4, c8 = tid & 15;
        *(uint4*)&esh[rn * 136 + c8 * 8] = et4[tid];
    }

    short8 afr[2][4];
    int row0 = base + w * 32 + nl;
    if (!src_bf16) {
        const float4* X4 = (const float4*)Xv;
        #pragma unroll
        for (int rt = 0; rt < 2; rt++) {
            int rr = row0 + rt * 16; if (rr > N_NODES - 1) rr = N_NODES - 1;
            const float4* px = X4 + (size_t)rr * 32 + q * 2;
            #pragma unroll
            for (int kc = 0; kc < 4; kc++) {
                float4 u = px[kc * 8], v = px[kc * 8 + 1];
                short8 f;
                f[0] = (short)bf16_rne(u.x); f[1] = (short)bf16_rne(u.y);
                f[2] = (short)bf16_rne(u.z); f[3] = (short)bf16_rne(u.w);
                f[4] = (short)bf16_rne(v.x); f[5] = (short)bf16_rne(v.y);
                f[6] = (short)bf16_rne(v.z); f[7] = (short)bf16_rne(v.w);
                afr[rt][kc] = f;
            }
        }
    } else {
        const unsigned short* Xb = (const unsigned short*)Xv;
        #pragma unroll
        for (int rt = 0; rt < 2; rt++) {
            int rr = row0 + rt * 16; if (rr > N_NODES - 1) rr = N_NODES - 1;
            #pragma unroll
            for (int kc = 0; kc < 4; kc++)
                afr[rt][kc] = *(const short8*)(Xb + (size_t)rr * 128 + kc * 32 + q * 8);
        }
    }

    floatx4 acc[2][8];
    floatx4 acc_e[2];
    #pragma unroll
    for (int rt = 0; rt < 2; rt++) {
        acc_e[rt] = (floatx4){0.f, 0.f, 0.f, 0.f};
        #pragma unroll
        for (int ct = 0; ct < 8; ct++)
            acc[rt][ct] = (floatx4){0.f, 0.f, 0.f, 0.f};
    }

    __syncthreads();

    int sw_hi = (nl >> 2) & 3, sw_lo = nl & 3;
    #pragma unroll
    for (int ct = 0; ct < 8; ct++) {
        int rbase = (ct * 16 + nl) * 128;
        #pragma unroll
        for (int kc = 0; kc < 4; kc++) {
            short8 b = *(const short8*)&wsh[rbase + ((kc ^ sw_hi) * 4 + (q ^ sw_lo)) * 8];
            acc[0][ct] = __builtin_amdgcn_mfma_f32_16x16x32_bf16(afr[0][kc], b, acc[0][ct], 0, 0, 0);
            acc[1][ct] = __builtin_amdgcn_mfma_f32_16x16x32_bf16(afr[1][kc], b, acc[1][ct], 0, 0, 0);
        }
    }
    #pragma unroll
    for (int kc = 0; kc < 4; kc++) {
        short8 e8 = *(const short8*)&esh[nl * 136 + (kc * 4 + q) * 8];
        acc_e[0] = __builtin_amdgcn_mfma_f32_16x16x32_bf16(afr[0][kc], e8, acc_e[0], 0, 0, 0);
        acc_e[1] = __builtin_amdgcn_mfma_f32_16x16x32_bf16(afr[1][kc], e8, acc_e[1], 0, 0, 0);
    }

    #pragma unroll
    for (int rt = 0; rt < 2; rt++) {
        #pragma unroll
        for (int r = 0; r < 4; r++) {
            int row = base + w * 32 + rt * 16 + q * 4 + r;
            bool valid = row < N_NODES;
            unsigned* hrow = Hb + (size_t)row * 64;
            #pragma unroll
            for (int ct = 0; ct < 8; ct++) {
                float vlo = acc[rt][ct][r];
                float vhi = __shfl_down(vlo, 1);
                if (valid && !(nl & 1)) hrow[ct * 8 + (nl >> 1)] = bfpack(vlo, vhi);
            }
            if (valid && nl < 8) {
                float v = acc_e[rt][r];
                if (nl < 4) EL[row * 4 + nl] = v;
                else        ER[row * 4 + (nl & 3)] = v;
            }
        }
    }
}

// ---------------- gather v3: fused softmax + aggregate ----------------
__global__ __launch_bounds__(256) void k_gather(const int* __restrict__ rs,
                                                const int* __restrict__ csr_src,
                                                const float* __restrict__ EL,
                                                const float* __restrict__ ER,
                                                const unsigned* __restrict__ Hb,
                                                const float* __restrict__ bias,
                                                void* __restrict__ out,
                                                int final_layer) {
    int wid = (blockIdx.x * blockDim.x + threadIdx.x) >> 6;
    int lane = threadIdx.x & 63;
    int g = lane >> 4, l16 = lane & 15;
    int h = l16 >> 2;
    int n0 = wid * 4;
    if (n0 >= N_NODES) return;
    int nend = min(n0 + 4, N_NODES);

    float bv[8];
    #pragma unroll
    for (int c = 0; c < 8; c++) bv[c] = bias[l16 * 8 + c];

    for (int n = n0; n < nend; n++) {
        int s = rs[n], e = rs[n + 1];
        float erh = ER[n * 4 + h];
        float acc[8];
        #pragma unroll
        for (int c = 0; c < 8; c++) acc[c] = 0.f;
        float sa = 0.f;

        for (int j = s; j < e; j += 8) {
            int j0 = j + g, j1 = j + 4 + g;
            uint4 p0 = make_uint4(0, 0, 0, 0), p1 = make_uint4(0, 0, 0, 0);
            float w0 = 0.f, w1 = 0.f;
            if (j0 < e) {
                int s0 = csr_src[j0];
                p0 = *(const uint4*)(Hb + (size_t)s0 * 64 + l16 * 4);
                w0 = __expf(lrelu(EL[s0 * 4 + h] + erh));
            }
            if (j1 < e) {
                int s1 = csr_src[j1];
                p1 = *(const uint4*)(Hb + (size_t)s1 * 64 + l16 * 4);
                w1 = __expf(lrelu(EL[s1 * 4 + h] + erh));
            }
            sa += w0 + w1;
            acc[0] = fmaf(bflo(p0.x), w0, acc[0]); acc[1] = fmaf(bfhi(p0.x), w0, acc[1]);
            acc[2] = fmaf(bflo(p0.y), w0, acc[2]); acc[3] = fmaf(bfhi(p0.y), w0, acc[3]);
            acc[4] = fmaf(bflo(p0.z), w0, acc[4]); acc[5] = fmaf(bfhi(p0.z), w0, acc[5]);
            acc[6] = fmaf(bflo(p0.w), w0, acc[6]); acc[7] = fmaf(bfhi(p0.w), w0, acc[7]);
            acc[0] = fmaf(bflo(p1.x), w1, acc[0]); acc[1] = fmaf(bfhi(p1.x), w1, acc[1]);
            acc[2] = fmaf(bflo(p1.y), w1, acc[2]); acc[3] = fmaf(bfhi(p1.y), w1, acc[3]);
            acc[4] = fmaf(bflo(p1.z), w1, acc[4]); acc[5] = fmaf(bfhi(p1.z), w1, acc[5]);
            acc[6] = fmaf(bflo(p1.w), w1, acc[6]); acc[7] = fmaf(bfhi(p1.w), w1, acc[7]);
        }

        #pragma unroll
        for (int c = 0; c < 8; c++) {
            acc[c] += __shfl_xor(acc[c], 16);
            acc[c] += __shfl_xor(acc[c], 32);
        }
        sa += __shfl_xor(sa, 16);
        sa += __shfl_xor(sa, 32);
        float inv = (e > s) ? 1.f / sa : 0.f;

        float r[8];
        #pragma unroll
        for (int c = 0; c < 8; c++) r[c] = acc[c] * inv + bv[c];

        if (!final_layer) {
            if (g == 0) {
                uint4 pk;
                pk.x = bfpack(fmaxf(r[0], 0.f), fmaxf(r[1], 0.f));
                pk.y = bfpack(fmaxf(r[2], 0.f), fmaxf(r[3], 0.f));
                pk.z = bfpack(fmaxf(r[4], 0.f), fmaxf(r[5], 0.f));
                pk.w = bfpack(fmaxf(r[6], 0.f), fmaxf(r[7], 0.f));
                *(uint4*)((unsigned*)out + (size_t)n * 64 + l16 * 4) = pk;
            }
        } else {
            #pragma unroll
            for (int c = 0; c < 8; c++) {
                r[c] += __shfl_xor(r[c], 4);
                r[c] += __shfl_xor(r[c], 8);
            }
            if (g == 0 && l16 < 4) {
                float* po = (float*)out + (size_t)n * 32 + l16 * 8;
                *(float4*)po = make_float4(0.25f * r[0], 0.25f * r[1], 0.25f * r[2], 0.25f * r[3]);
                *(float4*)(po + 4) = make_float4(0.25f * r[4], 0.25f * r[5], 0.25f * r[6], 0.25f * r[7]);
            }
        }
    }
}

extern "C" void kernel_launch(void* const* d_in, const int* in_sizes, int n_in,
                              void* d_out, int out_size, void* d_ws, size_t ws_size,
                              hipStream_t stream) {
    const float* feat = (const float*)d_in[0];
    const int* src = (const int*)d_in[1];
    const int* dst = (const int*)d_in[2];
    const float* W1 = (const float*)d_in[3];
    const float* al1 = (const float*)d_in[4];
    const float* ar1 = (const float*)d_in[5];
    const float* b1 = (const float*)d_in[6];
    const float* W2 = (const float*)d_in[7];
    const float* al2 = (const float*)d_in[8];
    const float* ar2 = (const float*)d_in[9];
    const float* b2 = (const float*)d_in[10];
    float* out = (float*)d_out;

    char* ws = (char*)d_ws;
    size_t off = 0;
    auto alloc = [&](size_t bytes) {
        void* p = ws + off;
        off += (bytes + 255) & ~(size_t)255;
        return p;
    };
    int* deg = (int*)alloc((size_t)N_NODES * 4);
    int* done = (int*)alloc(256);                       // contiguous after deg -> one memset
    int* rs = (int*)alloc(((size_t)N_NODES + 1) * 4);
    int* cursor = (int*)alloc((size_t)N_NODES * 4);
    int* bsums = (int*)alloc(128 * 4);
    int* csr_src = (int*)alloc((size_t)N_EDGES * 4);
    unsigned* Hb = (unsigned*)alloc((size_t)N_NODES * 64 * 4);     // bf16 H pairs
    float* el = (float*)alloc((size_t)N_NODES * 4 * 4);
    float* er = (float*)alloc((size_t)N_NODES * 4 * 4);
    unsigned* out1b = (unsigned*)alloc((size_t)N_NODES * 64 * 4);  // bf16 relu(out1)
    unsigned short* wt1 = (unsigned short*)alloc(128 * 128 * 2);
    unsigned short* wt2 = (unsigned short*)alloc(128 * 128 * 2);
    unsigned short* et1 = (unsigned short*)alloc(16 * 128 * 2);
    unsigned short* et2 = (unsigned short*)alloc(16 * 128 * 2);

    size_t zbytes = (size_t)((char*)done - (char*)deg) + 256;      // deg + done
    hipMemsetAsync(deg, 0, zbytes, stream);

    k_hist_wprep<<<3125 + 128 + 2, 256, 0, stream>>>(dst, deg, W1, al1, ar1,
                                                     W2, al2, ar2, wt1, wt2, et1, et2);
    k_scan<<<98, 256, 0, stream>>>(deg, rs, cursor, bsums, done);
    k_scatter<<<(N_EDGES + 255) / 256, 256, 0, stream>>>(src, dst, cursor, csr_src);

    int gemm_blocks = (N_NODES + 127) / 128;
    int gat_blocks = (N_NODES + 15) / 16;

    // layer 1
    k_gemm<<<gemm_blocks, 256, 0, stream>>>(feat, wt1, et1, Hb, el, er, 0);
    k_gather<<<gat_blocks, 256, 0, stream>>>(rs, csr_src, el, er, Hb, b1, out1b, 0);
    // layer 2
    k_gemm<<<gemm_blocks, 256, 0, stream>>>(out1b, wt2, et2, Hb, el, er, 1);
    k_gather<<<gat_blocks, 256, 0, stream>>>(rs, csr_src, el, er, Hb, b2, out, 1);
}

// Round 10
// 323.674 us; speedup vs baseline: 1.1213x; 1.0199x over previous
//
#include <hip/hip_runtime.h>
#include <math.h>

#define N_NODES 100000
#define N_EDGES 800000
#define NEG_SLOPE 0.2f
#define GEMM_BLOCKS 782            // ceil(100000/128)
#define HIST_BLOCKS 3125           // 800000/256

typedef __attribute__((ext_vector_type(8))) short short8;
typedef __attribute__((ext_vector_type(4))) float floatx4;

__device__ __forceinline__ float lrelu(float x) { return x > 0.f ? x : NEG_SLOPE * x; }

__device__ __forceinline__ unsigned bf16_rne(float f) {
    unsigned u = __float_as_uint(f);
    return (u + 0x7fffu + ((u >> 16) & 1u)) >> 16;
}
__device__ __forceinline__ unsigned bfpack(float lo, float hi) {
    return bf16_rne(lo) | (bf16_rne(hi) << 16);
}
__device__ __forceinline__ float bflo(unsigned p) { return __uint_as_float(p << 16); }
__device__ __forceinline__ float bfhi(unsigned p) { return __uint_as_float(p & 0xffff0000u); }

// ---------------- K1: W^T (0..127) + E (128..129) + zero deg (130..227) + zero done (228) ----------------
__global__ __launch_bounds__(256) void k_prep0(const float* __restrict__ W1,
                                               const float* __restrict__ al1,
                                               const float* __restrict__ ar1,
                                               const float* __restrict__ W2,
                                               const float* __restrict__ al2,
                                               const float* __restrict__ ar2,
                                               unsigned short* __restrict__ wt1,
                                               unsigned short* __restrict__ wt2,
                                               unsigned short* __restrict__ et1,
                                               unsigned short* __restrict__ et2,
                                               int* __restrict__ deg,
                                               int* __restrict__ done) {
    int b = blockIdx.x, tid = threadIdx.x;
    if (b < 128) {
        int t2 = b * 256 + tid;                   // 0..32767
        const float* W = (t2 < 16384) ? W1 : W2;
        unsigned short* wt = (t2 < 16384) ? wt1 : wt2;
        int t = t2 & 16383;
        int n = t >> 7, k = t & 127;
        wt[t] = (unsigned short)bf16_rne(W[k * 128 + n]);
    } else if (b < 130) {
        // E[n][k]: n<4 -> (W al)_head n ; 4<=n<8 -> (W ar)_head n-4 ; else 0
        const float* W = (b == 128) ? W1 : W2;
        const float* al = (b == 128) ? al1 : al2;
        const float* ar = (b == 128) ? ar1 : ar2;
        unsigned short* et = (b == 128) ? et1 : et2;
        for (int o = tid * 8; o < tid * 8 + 8; o++) {   // 2048 outputs
            int n = o >> 7, k = o & 127;
            float sacc = 0.f;
            if (n < 8) {
                const float* a = (n < 4) ? al : ar;
                int hh = n & 3;
                #pragma unroll 8
                for (int c = 0; c < 32; c++)
                    sacc += W[k * 128 + hh * 32 + c] * a[hh * 32 + c];
            }
            et[n * 128 + k] = (unsigned short)bf16_rne(sacc);
        }
    } else if (b < 228) {
        int i = (b - 130) * 1024 + tid * 4;
        if (i + 3 < N_NODES) *(int4*)&deg[i] = make_int4(0, 0, 0, 0);
        else { for (int j = i; j < N_NODES; j++) if (j >= 0) deg[j] = 0; }
    } else {
        if (tid < 64) done[tid] = 0;
    }
}

// ---------------- shared GEMM tile body (MFMA, direct-global A frags, el/er via MFMA) ----------------
__device__ __forceinline__ void gemm_tile(int base, const void* __restrict__ Xv,
                                          const unsigned short* __restrict__ wt,
                                          const unsigned short* __restrict__ et,
                                          unsigned* __restrict__ Hb,
                                          float* __restrict__ EL,
                                          float* __restrict__ ER,
                                          int src_bf16,
                                          unsigned short* wsh,   // [128*128]
                                          unsigned short* esh) { // [16*136]
    int tid = threadIdx.x;
    int w = tid >> 6, lane = tid & 63;
    int q = lane >> 4, nl = lane & 15;

    const uint4* wt4 = (const uint4*)wt;
    #pragma unroll
    for (int i = 0; i < 8; i++) {
        int idx = tid + i * 256;                // 0..2047 chunks of 8 shorts
        int rn = idx >> 4, c8 = idx & 15;
        int kc = c8 >> 2, qq = c8 & 3;
        int slot = rn * 128 + ((kc ^ ((rn >> 2) & 3)) * 4 + (qq ^ (rn & 3))) * 8;
        *(uint4*)&wsh[slot] = wt4[idx];
    }
    {
        const uint4* et4 = (const uint4*)et;
        int rn = tid >> 4, c8 = tid & 15;
        *(uint4*)&esh[rn * 136 + c8 * 8] = et4[tid];
    }

    short8 afr[2][4];
    int row0 = base + w * 32 + nl;
    if (!src_bf16) {
        const float4* X4 = (const float4*)Xv;
        #pragma unroll
        for (int rt = 0; rt < 2; rt++) {
            int rr = row0 + rt * 16; if (rr > N_NODES - 1) rr = N_NODES - 1;
            const float4* px = X4 + (size_t)rr * 32 + q * 2;
            #pragma unroll
            for (int kc = 0; kc < 4; kc++) {
                float4 u = px[kc * 8], v = px[kc * 8 + 1];
                short8 f;
                f[0] = (short)bf16_rne(u.x); f[1] = (short)bf16_rne(u.y);
                f[2] = (short)bf16_rne(u.z); f[3] = (short)bf16_rne(u.w);
                f[4] = (short)bf16_rne(v.x); f[5] = (short)bf16_rne(v.y);
                f[6] = (short)bf16_rne(v.z); f[7] = (short)bf16_rne(v.w);
                afr[rt][kc] = f;
            }
        }
    } else {
        const unsigned short* Xb = (const unsigned short*)Xv;
        #pragma unroll
        for (int rt = 0; rt < 2; rt++) {
            int rr = row0 + rt * 16; if (rr > N_NODES - 1) rr = N_NODES - 1;
            #pragma unroll
            for (int kc = 0; kc < 4; kc++)
                afr[rt][kc] = *(const short8*)(Xb + (size_t)rr * 128 + kc * 32 + q * 8);
        }
    }

    floatx4 acc[2][8];
    floatx4 acc_e[2];
    #pragma unroll
    for (int rt = 0; rt < 2; rt++) {
        acc_e[rt] = (floatx4){0.f, 0.f, 0.f, 0.f};
        #pragma unroll
        for (int ct = 0; ct < 8; ct++)
            acc[rt][ct] = (floatx4){0.f, 0.f, 0.f, 0.f};
    }

    __syncthreads();

    int sw_hi = (nl >> 2) & 3, sw_lo = nl & 3;
    #pragma unroll
    for (int ct = 0; ct < 8; ct++) {
        int rbase = (ct * 16 + nl) * 128;
        #pragma unroll
        for (int kc = 0; kc < 4; kc++) {
            short8 b = *(const short8*)&wsh[rbase + ((kc ^ sw_hi) * 4 + (q ^ sw_lo)) * 8];
            acc[0][ct] = __builtin_amdgcn_mfma_f32_16x16x32_bf16(afr[0][kc], b, acc[0][ct], 0, 0, 0);
            acc[1][ct] = __builtin_amdgcn_mfma_f32_16x16x32_bf16(afr[1][kc], b, acc[1][ct], 0, 0, 0);
        }
    }
    #pragma unroll
    for (int kc = 0; kc < 4; kc++) {
        short8 e8 = *(const short8*)&esh[nl * 136 + (kc * 4 + q) * 8];
        acc_e[0] = __builtin_amdgcn_mfma_f32_16x16x32_bf16(afr[0][kc], e8, acc_e[0], 0, 0, 0);
        acc_e[1] = __builtin_amdgcn_mfma_f32_16x16x32_bf16(afr[1][kc], e8, acc_e[1], 0, 0, 0);
    }

    #pragma unroll
    for (int rt = 0; rt < 2; rt++) {
        #pragma unroll
        for (int r = 0; r < 4; r++) {
            int row = base + w * 32 + rt * 16 + q * 4 + r;
            bool valid = row < N_NODES;
            unsigned* hrow = Hb + (size_t)row * 64;
            #pragma unroll
            for (int ct = 0; ct < 8; ct++) {
                float vlo = acc[rt][ct][r];
                float vhi = __shfl_down(vlo, 1);
                if (valid && !(nl & 1)) hrow[ct * 8 + (nl >> 1)] = bfpack(vlo, vhi);
            }
            if (valid && nl < 8) {
                float v = acc_e[rt][r];
                if (nl < 4) EL[row * 4 + nl] = v;
                else        ER[row * 4 + (nl & 3)] = v;
            }
        }
    }
}

// ---------------- K2: gemm layer-1 (blocks 0..781) + histogram (782..3906) ----------------
// Independent chains co-scheduled: MFMA waves (gemm) + atomic/latency waves (hist).
__global__ __launch_bounds__(256) void k_gemm_hist(const float* __restrict__ feat,
                                                   const unsigned short* __restrict__ wt1,
                                                   const unsigned short* __restrict__ et1,
                                                   unsigned* __restrict__ Hb,
                                                   float* __restrict__ EL,
                                                   float* __restrict__ ER,
                                                   const int* __restrict__ dst,
                                                   int* __restrict__ deg) {
    __shared__ unsigned short wsh[128 * 128];
    __shared__ unsigned short esh[16 * 136];
    int b = blockIdx.x;
    if (b < GEMM_BLOCKS) {
        gemm_tile(b * 128, feat, wt1, et1, Hb, EL, ER, 0, wsh, esh);
    } else {
        int e = (b - GEMM_BLOCKS) * 256 + threadIdx.x;
        if (e < N_EDGES) atomicAdd(&deg[dst[e]], 1);
    }
}

// ---------------- K6: plain gemm (layer 2) ----------------
__global__ __launch_bounds__(256) void k_gemm(const void* __restrict__ Xv,
                                              const unsigned short* __restrict__ wt,
                                              const unsigned short* __restrict__ et,
                                              unsigned* __restrict__ Hb,
                                              float* __restrict__ EL,
                                              float* __restrict__ ER,
                                              int src_bf16) {
    __shared__ unsigned short wsh[128 * 128];
    __shared__ unsigned short esh[16 * 136];
    gemm_tile(blockIdx.x * 128, Xv, wt, et, Hb, EL, ER, src_bf16, wsh, esh);
}

// ---------------- K3: exclusive scan over deg (98 blocks, one spin-sync) ----------------
__global__ __launch_bounds__(256) void k_scan(const int* __restrict__ deg,
                                              int* __restrict__ rs,
                                              int* __restrict__ cursor,
                                              int* __restrict__ bsums,
                                              int* __restrict__ done) {
    __shared__ int sd[256];
    int tid = threadIdx.x, b = blockIdx.x;
    int base = b * 1024 + tid * 4;
    int v0 = (base + 0 < N_NODES) ? deg[base + 0] : 0;
    int v1 = (base + 1 < N_NODES) ? deg[base + 1] : 0;
    int v2 = (base + 2 < N_NODES) ? deg[base + 2] : 0;
    int v3 = (base + 3 < N_NODES) ? deg[base + 3] : 0;
    int t = v0 + v1 + v2 + v3;
    sd[tid] = t;
    __syncthreads();
    int incl = t;
    for (int off = 1; off < 256; off <<= 1) {
        int x = (tid >= off) ? sd[tid - off] : 0;
        __syncthreads();
        incl += x;
        sd[tid] = incl;
        __syncthreads();
    }
    int excl = incl - t;

    if (tid == 255) {
        atomicExch(&bsums[b], incl);
        __threadfence();
        atomicAdd(done, 1);
    }
    if (tid == 0) {
        while (atomicAdd(done, 0) < 98) { }
    }
    __syncthreads();

    int bv = (tid < b) ? atomicAdd(&bsums[tid], 0) : 0;
    __syncthreads();
    sd[tid] = bv;
    __syncthreads();
    for (int off = 128; off > 0; off >>= 1) {
        if (tid < off) sd[tid] += sd[tid + off];
        __syncthreads();
    }
    int boff = sd[0];

    int p0 = excl + boff;
    if (base + 0 < N_NODES) { rs[base + 0] = p0; cursor[base + 0] = p0; }
    if (base + 1 < N_NODES) { rs[base + 1] = p0 + v0; cursor[base + 1] = p0 + v0; }
    if (base + 2 < N_NODES) { rs[base + 2] = p0 + v0 + v1; cursor[base + 2] = p0 + v0 + v1; }
    if (base + 3 < N_NODES) { rs[base + 3] = p0 + v0 + v1 + v2; cursor[base + 3] = p0 + v0 + v1 + v2; }
    if (b == 0 && tid == 0) rs[N_NODES] = N_EDGES;
}

// ---------------- K4: scatter ----------------
__global__ void k_scatter(const int* __restrict__ src, const int* __restrict__ dst,
                          int* __restrict__ cursor, int* __restrict__ csr_src) {
    int e = blockIdx.x * blockDim.x + threadIdx.x;
    if (e < N_EDGES) {
        int d = dst[e];
        int p = atomicAdd(&cursor[d], 1);
        csr_src[p] = src[e];
    }
}

// ---------------- K5/K7: gather v3 (fused softmax + aggregate) ----------------
__global__ __launch_bounds__(256) void k_gather(const int* __restrict__ rs,
                                                const int* __restrict__ csr_src,
                                                const float* __restrict__ EL,
                                                const float* __restrict__ ER,
                                                const unsigned* __restrict__ Hb,
                                                const float* __restrict__ bias,
                                                void* __restrict__ out,
                                                int final_layer) {
    int wid = (blockIdx.x * blockDim.x + threadIdx.x) >> 6;
    int lane = threadIdx.x & 63;
    int g = lane >> 4, l16 = lane & 15;
    int h = l16 >> 2;
    int n0 = wid * 4;
    if (n0 >= N_NODES) return;
    int nend = min(n0 + 4, N_NODES);

    float bv[8];
    #pragma unroll
    for (int c = 0; c < 8; c++) bv[c] = bias[l16 * 8 + c];

    for (int n = n0; n < nend; n++) {
        int s = rs[n], e = rs[n + 1];
        float erh = ER[n * 4 + h];
        float acc[8];
        #pragma unroll
        for (int c = 0; c < 8; c++) acc[c] = 0.f;
        float sa = 0.f;

        for (int j = s; j < e; j += 8) {
            int j0 = j + g, j1 = j + 4 + g;
            uint4 p0 = make_uint4(0, 0, 0, 0), p1 = make_uint4(0, 0, 0, 0);
            float w0 = 0.f, w1 = 0.f;
            if (j0 < e) {
                int s0 = csr_src[j0];
                p0 = *(const uint4*)(Hb + (size_t)s0 * 64 + l16 * 4);
                w0 = __expf(lrelu(EL[s0 * 4 + h] + erh));
            }
            if (j1 < e) {
                int s1 = csr_src[j1];
                p1 = *(const uint4*)(Hb + (size_t)s1 * 64 + l16 * 4);
                w1 = __expf(lrelu(EL[s1 * 4 + h] + erh));
            }
            sa += w0 + w1;
            acc[0] = fmaf(bflo(p0.x), w0, acc[0]); acc[1] = fmaf(bfhi(p0.x), w0, acc[1]);
            acc[2] = fmaf(bflo(p0.y), w0, acc[2]); acc[3] = fmaf(bfhi(p0.y), w0, acc[3]);
            acc[4] = fmaf(bflo(p0.z), w0, acc[4]); acc[5] = fmaf(bfhi(p0.z), w0, acc[5]);
            acc[6] = fmaf(bflo(p0.w), w0, acc[6]); acc[7] = fmaf(bfhi(p0.w), w0, acc[7]);
            acc[0] = fmaf(bflo(p1.x), w1, acc[0]); acc[1] = fmaf(bfhi(p1.x), w1, acc[1]);
            acc[2] = fmaf(bflo(p1.y), w1, acc[2]); acc[3] = fmaf(bfhi(p1.y), w1, acc[3]);
            acc[4] = fmaf(bflo(p1.z), w1, acc[4]); acc[5] = fmaf(bfhi(p1.z), w1, acc[5]);
            acc[6] = fmaf(bflo(p1.w), w1, acc[6]); acc[7] = fmaf(bfhi(p1.w), w1, acc[7]);
        }

        #pragma unroll
        for (int c = 0; c < 8; c++) {
            acc[c] += __shfl_xor(acc[c], 16);
            acc[c] += __shfl_xor(acc[c], 32);
        }
        sa += __shfl_xor(sa, 16);
        sa += __shfl_xor(sa, 32);
        float inv = (e > s) ? 1.f / sa : 0.f;

        float r[8];
        #pragma unroll
        for (int c = 0; c < 8; c++) r[c] = acc[c] * inv + bv[c];

        if (!final_layer) {
            if (g == 0) {
                uint4 pk;
                pk.x = bfpack(fmaxf(r[0], 0.f), fmaxf(r[1], 0.f));
                pk.y = bfpack(fmaxf(r[2], 0.f), fmaxf(r[3], 0.f));
                pk.z = bfpack(fmaxf(r[4], 0.f), fmaxf(r[5], 0.f));
                pk.w = bfpack(fmaxf(r[6], 0.f), fmaxf(r[7], 0.f));
                *(uint4*)((unsigned*)out + (size_t)n * 64 + l16 * 4) = pk;
            }
        } else {
            #pragma unroll
            for (int c = 0; c < 8; c++) {
                r[c] += __shfl_xor(r[c], 4);
                r[c] += __shfl_xor(r[c], 8);
            }
            if (g == 0 && l16 < 4) {
                float* po = (float*)out + (size_t)n * 32 + l16 * 8;
                *(float4*)po = make_float4(0.25f * r[0], 0.25f * r[1], 0.25f * r[2], 0.25f * r[3]);
                *(float4*)(po + 4) = make_float4(0.25f * r[4], 0.25f * r[5], 0.25f * r[6], 0.25f * r[7]);
            }
        }
    }
}

extern "C" void kernel_launch(void* const* d_in, const int* in_sizes, int n_in,
                              void* d_out, int out_size, void* d_ws, size_t ws_size,
                              hipStream_t stream) {
    const float* feat = (const float*)d_in[0];
    const int* src = (const int*)d_in[1];
    const int* dst = (const int*)d_in[2];
    const float* W1 = (const float*)d_in[3];
    const float* al1 = (const float*)d_in[4];
    const float* ar1 = (const float*)d_in[5];
    const float* b1 = (const float*)d_in[6];
    const float* W2 = (const float*)d_in[7];
    const float* al2 = (const float*)d_in[8];
    const float* ar2 = (const float*)d_in[9];
    const float* b2 = (const float*)d_in[10];
    float* out = (float*)d_out;

    char* ws = (char*)d_ws;
    size_t off = 0;
    auto alloc = [&](size_t bytes) {
        void* p = ws + off;
        off += (bytes + 255) & ~(size_t)255;
        return p;
    };
    int* deg = (int*)alloc((size_t)N_NODES * 4);
    int* done = (int*)alloc(256);
    int* rs = (int*)alloc(((size_t)N_NODES + 1) * 4);
    int* cursor = (int*)alloc((size_t)N_NODES * 4);
    int* bsums = (int*)alloc(128 * 4);
    int* csr_src = (int*)alloc((size_t)N_EDGES * 4);
    unsigned* Hb = (unsigned*)alloc((size_t)N_NODES * 64 * 4);     // bf16 H pairs
    float* el = (float*)alloc((size_t)N_NODES * 4 * 4);
    float* er = (float*)alloc((size_t)N_NODES * 4 * 4);
    unsigned* out1b = (unsigned*)alloc((size_t)N_NODES * 64 * 4);  // bf16 relu(out1)
    unsigned short* wt1 = (unsigned short*)alloc(128 * 128 * 2);
    unsigned short* wt2 = (unsigned short*)alloc(128 * 128 * 2);
    unsigned short* et1 = (unsigned short*)alloc(16 * 128 * 2);
    unsigned short* et2 = (unsigned short*)alloc(16 * 128 * 2);

    int gat_blocks = (N_NODES + 15) / 16;

    // K1: wprep + E + zero deg/done (no memset dispatch needed)
    k_prep0<<<229, 256, 0, stream>>>(W1, al1, ar1, W2, al2, ar2,
                                     wt1, wt2, et1, et2, deg, done);
    // K2: layer-1 GEMM co-scheduled with histogram (independent chains)
    k_gemm_hist<<<GEMM_BLOCKS + HIST_BLOCKS, 256, 0, stream>>>(feat, wt1, et1, Hb, el, er,
                                                               dst, deg);
    // K3: scan   K4: scatter
    k_scan<<<98, 256, 0, stream>>>(deg, rs, cursor, bsums, done);
    k_scatter<<<HIST_BLOCKS, 256, 0, stream>>>(src, dst, cursor, csr_src);
    // K5: gather layer 1
    k_gather<<<gat_blocks, 256, 0, stream>>>(rs, csr_src, el, er, Hb, b1, out1b, 0);
    // K6: gemm layer 2   K7: gather layer 2
    k_gemm<<<GEMM_BLOCKS, 256, 0, stream>>>(out1b, wt2, et2, Hb, el, er, 1);
    k_gather<<<gat_blocks, 256, 0, stream>>>(rs, csr_src, el, er, Hb, b2, out, 1);
}